// Round 4
// baseline (94.256 us; speedup 1.0000x reference)
//
#include <hip/hip_runtime.h>
#include <hip/hip_bf16.h>

#define EPS 1e-6f

typedef __attribute__((ext_vector_type(8))) short bf16x8;
typedef __attribute__((ext_vector_type(4))) float f32x4;

__device__ inline unsigned short f2bf(float f) {
  __hip_bfloat16 h = __float2bfloat16(f);
  return *reinterpret_cast<unsigned short*>(&h);
}

// ---------------------------------------------------------------------------
// Kernel A: per-speaker precompute (192 threads, float4-vectorized).
// Computes sums over M, ||sums||^2, per-utterance <d,sums>, ||d||^2.
// Writes: abf[i][d]  = bf16(dvec[i][d]/||dvec_i||)        (10240 x 768)
//         cnbf[n][d] = bf16(ctrd[n][d]/||ctrd_n||)        (1024 x 768)
//         simown[i]  = fp32 cosine(dvec_i, excl-centroid) (10240)
// Also zeroes out[0] (block 0) so no separate memset dispatch is needed.
// ---------------------------------------------------------------------------
__global__ void __launch_bounds__(192) ge2e_pre(
    const float* __restrict__ dv, unsigned short* __restrict__ abf,
    unsigned short* __restrict__ cnbf, float* __restrict__ simown,
    float* __restrict__ out) {
  const int n = blockIdx.x, t = threadIdx.x;  // t in [0,192): owns dims 4t..4t+3
  if (n == 0 && t == 0) out[0] = 0.f;  // consumed by ge2e_final (stream-ordered)
  const float* base = dv + (size_t)n * 7680;
  float4 v[10];
  float4 s4 = make_float4(0.f, 0.f, 0.f, 0.f);
#pragma unroll
  for (int m = 0; m < 10; ++m) {
    v[m] = *reinterpret_cast<const float4*>(&base[m * 768 + 4 * t]);
    s4.x += v[m].x; s4.y += v[m].y; s4.z += v[m].z; s4.w += v[m].w;
  }
  float part[21];
#pragma unroll
  for (int m = 0; m < 10; ++m) {
    part[m]      = v[m].x * s4.x + v[m].y * s4.y + v[m].z * s4.z + v[m].w * s4.w;
    part[10 + m] = v[m].x * v[m].x + v[m].y * v[m].y + v[m].z * v[m].z + v[m].w * v[m].w;
  }
  part[20] = s4.x * s4.x + s4.y * s4.y + s4.z * s4.z + s4.w * s4.w;
  // wave butterfly reduce (64 lanes)
#pragma unroll
  for (int k = 0; k < 21; ++k) {
#pragma unroll
    for (int off = 32; off >= 1; off >>= 1) part[k] += __shfl_xor(part[k], off);
  }
  __shared__ float red[3][21];
  __shared__ float bc[21];
  const int lane = t & 63, wid = t >> 6;
  if (lane == 0) {
#pragma unroll
    for (int k = 0; k < 21; ++k) red[wid][k] = part[k];
  }
  __syncthreads();
  if (t < 21) bc[t] = red[0][t] + red[1][t] + red[2][t];
  __syncthreads();
  const float ss = bc[20];
  // centroid = sums/10; cnorm = max(|ctrd|, eps) -> divide sums by max(|sums|, 10*eps)
  const float rc = 1.0f / fmaxf(sqrtf(ss), 10.0f * EPS);
  {
    short4 c;
    c.x = (short)f2bf(s4.x * rc); c.y = (short)f2bf(s4.y * rc);
    c.z = (short)f2bf(s4.z * rc); c.w = (short)f2bf(s4.w * rc);
    *reinterpret_cast<short4*>(&cnbf[n * 768 + 4 * t]) = c;
  }
#pragma unroll
  for (int m = 0; m < 10; ++m) {
    float rd = 1.0f / fmaxf(sqrtf(bc[10 + m]), EPS);
    short4 a;
    a.x = (short)f2bf(v[m].x * rd); a.y = (short)f2bf(v[m].y * rd);
    a.z = (short)f2bf(v[m].z * rd); a.w = (short)f2bf(v[m].w * rd);
    *reinterpret_cast<short4*>(&abf[(size_t)(n * 10 + m) * 768 + 4 * t]) = a;
  }
  if (t < 10) {
    float dot = bc[t], sq = bc[10 + t];
    float dn = fmaxf(sqrtf(sq), EPS);
    float en = fmaxf(sqrtf(fmaxf(ss - 2.f * dot + sq, 0.f)) * (1.0f / 9.0f), EPS);
    simown[n * 10 + t] = ((dot - sq) * (1.0f / 9.0f)) / (dn * en);
  }
}

// ---------------------------------------------------------------------------
// Kernel B: bf16 MFMA GEMM (10240x1024x768) fused with diagonal replacement
// and per-row partial logsumexp.
// Round-4 structure: BARRIER-FREE, LDS-FREE. Both operands are L2/L3-resident
// (A ~2 MB/XCD after swizzle, B 1.5 MB total), so each wave loads its MFMA
// fragments directly from global into a register double-buffer (16x64B
// segments per global_load_dwordx4). No __shared__, no __syncthreads, no
// vmcnt drains: waves are independent self-paced pipelines and the compiler
// schedules loads under MFMAs (m114 implicit overlap). Full 24-step unroll ->
// loads use base+imm offsets. 128x128 tile, 4 waves 2x2, 640 blocks with
// bijective XCD swizzle (640 = 8 x 80).
// ---------------------------------------------------------------------------
__global__ void __launch_bounds__(256) ge2e_gemm(
    const unsigned short* __restrict__ abf, const unsigned short* __restrict__ cnbf,
    const float* __restrict__ simown, const float* __restrict__ wp,
    float2* __restrict__ lse) {
  const int t = threadIdx.x;
  const int lane = t & 63, wid = t >> 6;
  const int bx = blockIdx.x;
  const int wg = (bx & 7) * 80 + (bx >> 3);  // bijective XCD swizzle
  const int rb = wg >> 3, cb = wg & 7;
  const int row0 = rb * 128, col0 = cb * 128;
  const int wr = wid >> 1, wc = wid & 1;
  const int l15 = lane & 15, lg = lane >> 4;

  // Lane's fragment base: row (row0 + wr*64 + i*16 + l15), k-chunk lg*8.
  // Frag i offset = i*16 rows * 768 = i*12288 elems; K-step kk adds kk elems.
  const unsigned short* aBase = abf + (size_t)(row0 + wr * 64 + l15) * 768 + lg * 8;
  const unsigned short* bBase = cnbf + (size_t)(col0 + wc * 64 + l15) * 768 + lg * 8;

  f32x4 acc[4][4];
#pragma unroll
  for (int i = 0; i < 4; ++i)
#pragma unroll
    for (int j = 0; j < 4; ++j) acc[i][j] = (f32x4){0.f, 0.f, 0.f, 0.f};

#define LOADF(SA, SB, KK)                                                     \
  do {                                                                        \
    _Pragma("unroll") for (int i_ = 0; i_ < 4; ++i_)                          \
        SA[i_] = *(const bf16x8*)(aBase + (size_t)i_ * 12288 + (KK));         \
    _Pragma("unroll") for (int j_ = 0; j_ < 4; ++j_)                          \
        SB[j_] = *(const bf16x8*)(bBase + (size_t)j_ * 12288 + (KK));         \
  } while (0)

#define MFMA_STEP(SA, SB)                                                     \
  do {                                                                        \
    _Pragma("unroll") for (int i_ = 0; i_ < 4; ++i_)                          \
      _Pragma("unroll") for (int j_ = 0; j_ < 4; ++j_)                        \
        acc[i_][j_] = __builtin_amdgcn_mfma_f32_16x16x32_bf16(                \
            SA[i_], SB[j_], acc[i_][j_], 0, 0, 0);                            \
  } while (0)

  bf16x8 aA[4], bA[4], aB[4], bB[4];
  LOADF(aA, bA, 0);
#pragma unroll
  for (int kk = 0; kk < 768; kk += 64) {
    LOADF(aB, bB, kk + 32);          // prefetch next K-step (last: kk=736, valid)
    MFMA_STEP(aA, bA);
    if (kk + 64 < 768) LOADF(aA, bA, kk + 64);  // folds statically
    MFMA_STEP(aB, bB);
  }
#undef LOADF
#undef MFMA_STEP

  // Epilogue: logits = w*cos (bias b cancels in log_softmax - pick), diagonal
  // replaced by fp32 sim_own; per-row (max, expsum) over this wave's 64 cols.
  const float wv = wp[0];
  const int R0 = row0 + wr * 64, C0 = col0 + wc * 64;
#pragma unroll
  for (int i = 0; i < 4; ++i) {
#pragma unroll
    for (int r = 0; r < 4; ++r) {
      const int grow = R0 + i * 16 + lg * 4 + r;
      const int ownc = grow / 10;  // own speaker column
      float vj[4];
#pragma unroll
      for (int j = 0; j < 4; ++j) {
        const int gcol = C0 + j * 16 + l15;
        float vv = wv * acc[i][j][r];
        if (gcol == ownc) vv = wv * simown[grow];
        vj[j] = vv;
      }
      float mx = fmaxf(fmaxf(vj[0], vj[1]), fmaxf(vj[2], vj[3]));
#pragma unroll
      for (int off = 1; off < 16; off <<= 1) mx = fmaxf(mx, __shfl_xor(mx, off, 16));
      float sm = __expf(vj[0] - mx) + __expf(vj[1] - mx) +
                 __expf(vj[2] - mx) + __expf(vj[3] - mx);
#pragma unroll
      for (int off = 1; off < 16; off <<= 1) sm += __shfl_xor(sm, off, 16);
      if (l15 == 0) lse[(size_t)grow * 16 + cb * 2 + wc] = make_float2(mx, sm);
    }
  }
}

// ---------------------------------------------------------------------------
// Kernel C: combine 16 (m,s) partials per row, loss = m + log(s) - w*simown,
// sum all 10240 losses into d_out.
// ---------------------------------------------------------------------------
__global__ void __launch_bounds__(256) ge2e_final(
    const float2* __restrict__ lse, const float* __restrict__ simown,
    const float* __restrict__ wp, float* __restrict__ out) {
  const int i = blockIdx.x * 256 + threadIdx.x;  // 0..10239
  const float wv = wp[0];
  float2 p[16];
  float m = -1e30f;
#pragma unroll
  for (int k = 0; k < 16; ++k) {
    p[k] = lse[(size_t)i * 16 + k];
    m = fmaxf(m, p[k].x);
  }
  float s = 0.f;
#pragma unroll
  for (int k = 0; k < 16; ++k) s += p[k].y * __expf(p[k].x - m);
  float loss = m + logf(s) - wv * simown[i];
#pragma unroll
  for (int off = 32; off >= 1; off >>= 1) loss += __shfl_xor(loss, off);
  __shared__ float red[4];
  const int lane = threadIdx.x & 63, wid = threadIdx.x >> 6;
  if (lane == 0) red[wid] = loss;
  __syncthreads();
  if (threadIdx.x == 0) atomicAdd(out, red[0] + red[1] + red[2] + red[3]);
}

extern "C" void kernel_launch(void* const* d_in, const int* in_sizes, int n_in,
                              void* d_out, int out_size, void* d_ws, size_t ws_size,
                              hipStream_t stream) {
  (void)in_sizes; (void)n_in; (void)out_size; (void)ws_size;
  const float* dv = (const float*)d_in[0];
  const float* wp = (const float*)d_in[1];
  // d_in[2] (bias b) cancels exactly in -log_softmax[own]; unused.

  unsigned short* abf = (unsigned short*)d_ws;                        // 15,728,640 B
  unsigned short* cnbf = (unsigned short*)((char*)d_ws + 15728640);   //  1,572,864 B
  float* simown = (float*)((char*)d_ws + 17301504);                   //     40,960 B
  float2* lse = (float2*)((char*)d_ws + 17342464);                    //  1,310,720 B
  float* out = (float*)d_out;

  ge2e_pre<<<1024, 192, 0, stream>>>(dv, abf, cnbf, simown, out);
  ge2e_gemm<<<640, 256, 0, stream>>>(abf, cnbf, simown, wp, lse);
  ge2e_final<<<40, 256, 0, stream>>>(lse, simown, wp, out);
}

// Round 5
// 50.884 us; speedup vs baseline: 1.8524x; 1.8524x over previous
//
#include <hip/hip_runtime.h>
#include <hip/hip_bf16.h>

#define EPS 1e-6f

typedef __attribute__((ext_vector_type(8))) short bf16x8;
typedef __attribute__((ext_vector_type(4))) float f32x4;

__device__ inline unsigned short f2bf(float f) {
  __hip_bfloat16 h = __float2bfloat16(f);
  return *reinterpret_cast<unsigned short*>(&h);
}

// ---------------------------------------------------------------------------
// Kernel A: per-speaker precompute (192 threads, float4-vectorized).
// Writes: abf[i][d]  = bf16(dvec[i][d]/||dvec_i||)        (10240 x 768)
//         cnbf[n][d] = bf16(ctrd[n][d]/||ctrd_n||)        (1024 x 768)
//         simown[i]  = fp32 cosine(dvec_i, excl-centroid) (10240)
// Also zeroes rowsum[10240] and out[0] (no separate memset dispatches).
// ---------------------------------------------------------------------------
__global__ void __launch_bounds__(192) ge2e_pre(
    const float* __restrict__ dv, unsigned short* __restrict__ abf,
    unsigned short* __restrict__ cnbf, float* __restrict__ simown,
    float* __restrict__ rowsum, float* __restrict__ out) {
  const int n = blockIdx.x, t = threadIdx.x;  // t in [0,192): owns dims 4t..4t+3
  if (n == 0 && t == 0) out[0] = 0.f;  // consumed by ge2e_final (stream-ordered)
  const float* base = dv + (size_t)n * 7680;
  float4 v[10];
  float4 s4 = make_float4(0.f, 0.f, 0.f, 0.f);
#pragma unroll
  for (int m = 0; m < 10; ++m) {
    v[m] = *reinterpret_cast<const float4*>(&base[m * 768 + 4 * t]);
    s4.x += v[m].x; s4.y += v[m].y; s4.z += v[m].z; s4.w += v[m].w;
  }
  float part[21];
#pragma unroll
  for (int m = 0; m < 10; ++m) {
    part[m]      = v[m].x * s4.x + v[m].y * s4.y + v[m].z * s4.z + v[m].w * s4.w;
    part[10 + m] = v[m].x * v[m].x + v[m].y * v[m].y + v[m].z * v[m].z + v[m].w * v[m].w;
  }
  part[20] = s4.x * s4.x + s4.y * s4.y + s4.z * s4.z + s4.w * s4.w;
  // wave butterfly reduce (64 lanes)
#pragma unroll
  for (int k = 0; k < 21; ++k) {
#pragma unroll
    for (int off = 32; off >= 1; off >>= 1) part[k] += __shfl_xor(part[k], off);
  }
  __shared__ float red[3][21];
  __shared__ float bc[21];
  const int lane = t & 63, wid = t >> 6;
  if (lane == 0) {
#pragma unroll
    for (int k = 0; k < 21; ++k) red[wid][k] = part[k];
  }
  __syncthreads();
  if (t < 21) bc[t] = red[0][t] + red[1][t] + red[2][t];
  __syncthreads();
  const float ss = bc[20];
  // centroid = sums/10; cnorm = max(|ctrd|, eps) -> divide sums by max(|sums|, 10*eps)
  const float rc = 1.0f / fmaxf(sqrtf(ss), 10.0f * EPS);
  {
    short4 c;
    c.x = (short)f2bf(s4.x * rc); c.y = (short)f2bf(s4.y * rc);
    c.z = (short)f2bf(s4.z * rc); c.w = (short)f2bf(s4.w * rc);
    *reinterpret_cast<short4*>(&cnbf[n * 768 + 4 * t]) = c;
  }
#pragma unroll
  for (int m = 0; m < 10; ++m) {
    float rd = 1.0f / fmaxf(sqrtf(bc[10 + m]), EPS);
    short4 a;
    a.x = (short)f2bf(v[m].x * rd); a.y = (short)f2bf(v[m].y * rd);
    a.z = (short)f2bf(v[m].z * rd); a.w = (short)f2bf(v[m].w * rd);
    *reinterpret_cast<short4*>(&abf[(size_t)(n * 10 + m) * 768 + 4 * t]) = a;
  }
  if (t < 10) {
    float dot = bc[t], sq = bc[10 + t];
    float dn = fmaxf(sqrtf(sq), EPS);
    float en = fmaxf(sqrtf(fmaxf(ss - 2.f * dot + sq, 0.f)) * (1.0f / 9.0f), EPS);
    simown[n * 10 + t] = ((dot - sq) * (1.0f / 9.0f)) / (dn * en);
    rowsum[n * 10 + t] = 0.f;  // accumulated by ge2e_gemm atomics
  }
}

// ---------------------------------------------------------------------------
// Kernel B: bf16 MFMA GEMM (10240x1024x768) fused with diagonal replacement
// and direct exp-sum accumulation (no max pass: |w*sim| <= ~10.1, exp is fp32
// safe; bias b cancels in log_softmax - pick).
// Round-5 structure: 64x128 tile, BK=32, 4 waves (2x2, 32x64 per wave),
// double-buffered LDS (24 KB), depth-1 prefetch + vmcnt(0)/s_barrier per
// K-step (round-2's proven schedule). 1280 blocks = EXACTLY 5 blocks/CU
// (balanced, 20 waves/CU of barrier-stall hiding). Bijective XCD swizzle
// (1280 = 8 x 160).
// ---------------------------------------------------------------------------
__global__ void __launch_bounds__(256, 5) ge2e_gemm(
    const unsigned short* __restrict__ abf, const unsigned short* __restrict__ cnbf,
    const float* __restrict__ simown, const float* __restrict__ wp,
    float* __restrict__ rowsum) {
  __shared__ unsigned short As[2][64 * 32];    // 4 KB per buffer
  __shared__ unsigned short Bs[2][128 * 32];   // 8 KB per buffer
  const int t = threadIdx.x;
  const int lane = t & 63, wid = t >> 6;
  const int bx = blockIdx.x;
  const int wg = (bx & 7) * 160 + (bx >> 3);  // bijective XCD swizzle
  const int rb = wg >> 3, cb = wg & 7;
  const int row0 = rb * 64, col0 = cb * 128;
  const int wr = wid >> 1, wc = wid & 1;       // wave tile: rows 32, cols 64
  const int l15 = lane & 15, lg = lane >> 4;

  f32x4 acc[2][4];
#pragma unroll
  for (int i = 0; i < 2; ++i)
#pragma unroll
    for (int j = 0; j < 4; ++j) acc[i][j] = (f32x4){0.f, 0.f, 0.f, 0.f};

  // 12 x 1KB segments per tile-pair: segs 0..3 = A (64x32), 4..11 = B (128x32).
  // Wave `wid` stages segments 3*wid .. 3*wid+2 (wave-uniform LDS base).
  auto STAGE = [&](int buf, int kk) {
#pragma unroll
    for (int jj = 0; jj < 3; ++jj) {
      const int s = wid * 3 + jj;
      if (s < 4) {
        const int c = s * 64 + lane;  // 16B chunk in A tile
        const int r = c >> 2, kc = c & 3;
        const unsigned short* src = abf + (size_t)(row0 + r) * 768 + kk + kc * 8;
        unsigned short* dst = &As[buf][s * 512];
        __builtin_amdgcn_global_load_lds(
            (const __attribute__((address_space(1))) unsigned int*)src,
            (__attribute__((address_space(3))) unsigned int*)dst, 16, 0, 0);
      } else {
        const int c = (s - 4) * 64 + lane;  // 16B chunk in B tile
        const int r = c >> 2, kc = c & 3;
        const unsigned short* src = cnbf + (size_t)(col0 + r) * 768 + kk + kc * 8;
        unsigned short* dst = &Bs[buf][(s - 4) * 512];
        __builtin_amdgcn_global_load_lds(
            (const __attribute__((address_space(1))) unsigned int*)src,
            (__attribute__((address_space(3))) unsigned int*)dst, 16, 0, 0);
      }
    }
  };
  auto COMPUTE = [&](int buf) {
    bf16x8 af[2], bfr[4];
#pragma unroll
    for (int i = 0; i < 2; ++i)
      af[i] = *(const bf16x8*)&As[buf][(wr * 32 + i * 16 + l15) * 32 + lg * 8];
#pragma unroll
    for (int j = 0; j < 4; ++j)
      bfr[j] = *(const bf16x8*)&Bs[buf][(wc * 64 + j * 16 + l15) * 32 + lg * 8];
#pragma unroll
    for (int i = 0; i < 2; ++i)
#pragma unroll
      for (int j = 0; j < 4; ++j)
        acc[i][j] = __builtin_amdgcn_mfma_f32_16x16x32_bf16(af[i], bfr[j], acc[i][j], 0, 0, 0);
  };

  // prologue
  STAGE(0, 0);
  asm volatile("s_waitcnt vmcnt(0)" ::: "memory");
  __builtin_amdgcn_s_barrier();
  int cur = 0;
  for (int tt = 0; tt < 23; ++tt) {
    STAGE(cur ^ 1, (tt + 1) * 32);
    COMPUTE(cur);  // compiler inserts lgkmcnt for ds_read->MFMA deps
    asm volatile("s_waitcnt vmcnt(0)" ::: "memory");
    __builtin_amdgcn_s_barrier();
    cur ^= 1;
  }
  COMPUTE(cur);

  // Epilogue: vv = w*cos (diagonal: fp32 sim_own); rowsum[grow] += sum_j exp(vv)
  // No max subtraction needed: |vv| <= ~10.1 -> exp in [4e-5, 2.5e4], fp32-safe.
  const float wv = wp[0];
  const int R0 = row0 + wr * 32, C0 = col0 + wc * 64;
#pragma unroll
  for (int i = 0; i < 2; ++i) {
#pragma unroll
    for (int r = 0; r < 4; ++r) {
      const int grow = R0 + i * 16 + lg * 4 + r;
      const int ownc = grow / 10;  // own speaker column
      float sm = 0.f;
#pragma unroll
      for (int j = 0; j < 4; ++j) {
        const int gcol = C0 + j * 16 + l15;
        float vv = wv * acc[i][j][r];
        if (gcol == ownc) vv = wv * simown[grow];
        sm += __expf(vv);
      }
#pragma unroll
      for (int off = 1; off < 16; off <<= 1) sm += __shfl_xor(sm, off, 16);
      if (l15 == 0) atomicAdd(&rowsum[grow], sm);
    }
  }
}

// ---------------------------------------------------------------------------
// Kernel C: loss_i = log(rowsum_i) - w*simown_i; sum over 10240 into d_out.
// ---------------------------------------------------------------------------
__global__ void __launch_bounds__(256) ge2e_final(
    const float* __restrict__ rowsum, const float* __restrict__ simown,
    const float* __restrict__ wp, float* __restrict__ out) {
  const int i = blockIdx.x * 256 + threadIdx.x;  // 0..10239
  const float wv = wp[0];
  float loss = logf(rowsum[i]) - wv * simown[i];
#pragma unroll
  for (int off = 32; off >= 1; off >>= 1) loss += __shfl_xor(loss, off);
  __shared__ float red[4];
  const int lane = threadIdx.x & 63, wid = threadIdx.x >> 6;
  if (lane == 0) red[wid] = loss;
  __syncthreads();
  if (threadIdx.x == 0) atomicAdd(out, red[0] + red[1] + red[2] + red[3]);
}

extern "C" void kernel_launch(void* const* d_in, const int* in_sizes, int n_in,
                              void* d_out, int out_size, void* d_ws, size_t ws_size,
                              hipStream_t stream) {
  (void)in_sizes; (void)n_in; (void)out_size; (void)ws_size;
  const float* dv = (const float*)d_in[0];
  const float* wp = (const float*)d_in[1];
  // d_in[2] (bias b) cancels exactly in -log_softmax[own]; unused.

  unsigned short* abf = (unsigned short*)d_ws;                        // 15,728,640 B
  unsigned short* cnbf = (unsigned short*)((char*)d_ws + 15728640);   //  1,572,864 B
  float* simown = (float*)((char*)d_ws + 17301504);                   //     40,960 B
  float* rowsum = (float*)((char*)d_ws + 17342464);                   //     40,960 B
  float* out = (float*)d_out;

  ge2e_pre<<<1024, 192, 0, stream>>>(dv, abf, cnbf, simown, rowsum, out);
  ge2e_gemm<<<1280, 256, 0, stream>>>(abf, cnbf, simown, wp, rowsum);
  ge2e_final<<<40, 256, 0, stream>>>(rowsum, simown, wp, out);
}